// Round 21
// baseline (199.351 us; speedup 1.0000x reference)
//
#include <hip/hip_runtime.h>

typedef unsigned short u16;
typedef unsigned int u32;
typedef __bf16 bf16x8 __attribute__((ext_vector_type(8)));
typedef float f32x4 __attribute__((ext_vector_type(4)));
typedef u16 u16x8 __attribute__((ext_vector_type(8)));
typedef u16 u16x4 __attribute__((ext_vector_type(4)));

typedef __attribute__((address_space(1))) const unsigned char gc_u8;
typedef __attribute__((address_space(3))) unsigned char lds_u8;

__device__ inline void gload16(const void* g, void* l) {
    __builtin_amdgcn_global_load_lds((gc_u8*)g, (lds_u8*)l, 16, 0, 0);
}
__device__ inline u16 f2bf(float f) {
    union { __bf16 h; u16 u; } c; c.h = (__bf16)f; return c.u;
}
__device__ inline float bf2f(u16 u) {
    union { u16 u[2]; float f; } c; c.u[0] = 0; c.u[1] = u; return c.f;
}
__device__ inline void hard_barrier() {
    __builtin_amdgcn_sched_barrier(0);
    __builtin_amdgcn_s_barrier();
    __builtin_amdgcn_sched_barrier(0);
}
#define WAIT_LGKM0() asm volatile("s_waitcnt lgkmcnt(0)" ::: "memory")
#define WAIT_VMCNT(n) asm volatile("s_waitcnt vmcnt(" #n ")" ::: "memory")

// ---------------- weight fp32 -> bf16 convert ----------------
__global__ __launch_bounds__(256) void cvt4(const float* __restrict__ s0,
                                            const float* __restrict__ s1,
                                            const float* __restrict__ s2,
                                            const float* __restrict__ s3,
                                            u16* __restrict__ d0, u16* __restrict__ d1,
                                            u16* __restrict__ d2, u16* __restrict__ d3,
                                            int n) {
    const int y = blockIdx.y;
    const float* src = (y == 0) ? s0 : (y == 1) ? s1 : (y == 2) ? s2 : s3;
    u16* dst = (y == 0) ? d0 : (y == 1) ? d1 : (y == 2) ? d2 : d3;
    int i = (blockIdx.x * 256 + threadIdx.x) * 4;
    if (i < n) {
        float4 f = *reinterpret_cast<const float4*>(src + i);
        u16x4 u = { f2bf(f.x), f2bf(f.y), f2bf(f.z), f2bf(f.w) };
        *reinterpret_cast<u16x4*>(dst + i) = u;
    }
}

// ---------------- per-token compacted destination index (order-preserving) ----------------
__global__ __launch_bounds__(256) void build_dtok(const int* __restrict__ mask,
                                                  int* __restrict__ dtok,
                                                  int* __restrict__ NbA) {
    __shared__ u32 W[64];
    __shared__ u32 Wpre[65];
    const int b = blockIdx.x, t = threadIdx.x;
    const int* mrow = mask + b * 2048;
    if (t < 64) {
        u32 wv = 0;
#pragma unroll 8
        for (int j = 0; j < 32; j++) wv |= (mrow[t * 32 + j] ? 1u : 0u) << j;
        W[t] = wv;
    }
    __syncthreads();
    if (t == 0) {
        u32 s = 0;
        for (int i = 0; i < 64; i++) { Wpre[i] = s; s += __popc(W[i]); }
        Wpre[64] = s;
        NbA[b] = (int)s;
    }
    __syncthreads();
    const int Nb = (int)Wpre[64];
    const int pad = (Nb + 127) & ~127;
#pragma unroll
    for (int i = 0; i < 8; i++) {
        const int s = t * 8 + i;
        const u32 word = W[s >> 5];
        const int pre = (int)Wpre[s >> 5] + __popc(word & ((1u << (s & 31)) - 1u));
        int v;
        if ((word >> (s & 31)) & 1u) {
            v = pre;
        } else {
            const int slot = Nb + (s - pre);
            v = (slot < pad) ? -(slot + 2) : -1;
        }
        dtok[b * 2048 + s] = v;
    }
}

// ---------------- merged QKV GEMM: 2-deep A prefetch, swizzled bf16 LDS, compacting epilogue ----------------
// Tile t's f32 A regs live in fA[t&1]; loaded at iter t-2, cvtwritten at iter t-1.
// vmcnt ledger (steady): before wait = f32(i+1)x4 + B(i)x2 + f32(i+2)x4 + B(i+1)x2 = 12;
// WAIT_VMCNT(6) drains {f32(i+1), B(i)} (both needed now), leaves 6 flying.
// Tail i+2>=NS: outstanding = f32(i+1)x4 + B(i)x2 + B(i+1)x2 = 8 -> WAIT_VMCNT(2).
__global__ __launch_bounds__(256) void gemm_qkv(const float* __restrict__ Aq,
                                                const float* __restrict__ Ak,
                                                const float* __restrict__ Av,
                                                const u16* __restrict__ Bq,
                                                const u16* __restrict__ Bk,
                                                const u16* __restrict__ Bv,
                                                const float* __restrict__ bq,
                                                const float* __restrict__ bk,
                                                const float* __restrict__ bv,
                                                const int* __restrict__ dtok,
                                                u16* __restrict__ Cq,
                                                u16* __restrict__ Ck,
                                                u16* __restrict__ Cvp,
                                                int M, int N, int K) {
    __shared__ __align__(16) u16 As[2][128][32];
    __shared__ __align__(16) u16 Bs[2][128][32];
    const int z = blockIdx.z;
    const float* A = (z == 0) ? Aq : (z == 1) ? Ak : Av;
    const u16* B = (z == 0) ? Bq : (z == 1) ? Bk : Bv;
    const float* bias = (z == 0) ? bq : (z == 1) ? bk : bv;

    const int t = threadIdx.x, lane = t & 63, w = t >> 6;
    const int wr = w >> 1, wc = w & 1;
    const int l15 = lane & 15, l16 = lane >> 4;
    const int nwg = gridDim.x, ntiles = N >> 7;
    const int wg = blockIdx.x, chunk = nwg >> 3;
    const int swz = (wg & 7) * chunk + (wg >> 3);
    const int bm = (swz / ntiles) * 128, bn = (swz % ntiles) * 128;
    const int row = t >> 1, cc = (t & 1) * 16;              // A reg-stage coords
    const int akey = (t >> 2) & 3, agb = (t & 1) * 2;       // A write swizzle
    const int srow = w * 16 + (lane >> 2);
    const int sgrB = ((lane & 3) ^ ((lane >> 3) & 3)) * 8;  // B swizzled source granule
    const int gswB = (l16 ^ ((l15 >> 1) & 3)) * 8;          // swizzled read granule (A and B)
    const u16* Bb = B + (size_t)bn * K;

    f32x4 acc[4][4];
#pragma unroll
    for (int i = 0; i < 4; i++)
#pragma unroll
        for (int j = 0; j < 4; j++) acc[i][j] = (f32x4){0.f, 0.f, 0.f, 0.f};

    float4 fA0[4], fA1[4];   // named double-buffer (static indexing only)
    auto loadA = [&](float4* bf, int k0) {
        const float* Ap = A + (size_t)(bm + row) * K + k0 + cc;
        bf[0] = *(const float4*)(Ap);
        bf[1] = *(const float4*)(Ap + 4);
        bf[2] = *(const float4*)(Ap + 8);
        bf[3] = *(const float4*)(Ap + 12);
    };
    auto cvtwrite = [&](int c, const float4* bf) {
        u16x8 a0 = (u16x8){f2bf(bf[0].x), f2bf(bf[0].y), f2bf(bf[0].z), f2bf(bf[0].w),
                           f2bf(bf[1].x), f2bf(bf[1].y), f2bf(bf[1].z), f2bf(bf[1].w)};
        u16x8 a1 = (u16x8){f2bf(bf[2].x), f2bf(bf[2].y), f2bf(bf[2].z), f2bf(bf[2].w),
                           f2bf(bf[3].x), f2bf(bf[3].y), f2bf(bf[3].z), f2bf(bf[3].w)};
        *(u16x8*)&As[c][row][((agb + 0) ^ akey) * 8] = a0;
        *(u16x8*)&As[c][row][((agb + 1) ^ akey) * 8] = a1;
    };
    auto stageB = [&](int c, int k0) {
        gload16(Bb + (size_t)srow * K + k0 + sgrB,        &Bs[c][w * 16][0]);
        gload16(Bb + (size_t)(64 + srow) * K + k0 + sgrB, &Bs[c][64 + w * 16][0]);
    };

    const int NS = K >> 5;   // 32
    // prologue: tile 0 staged fully; tile 1 f32 in flight (drained by syncthreads)
    loadA(fA0, 0);
    stageB(0, 0);
    WAIT_VMCNT(2);      // f32(0) landed; B(0) flying
    cvtwrite(0, fA0);
    loadA(fA1, 32);
    __syncthreads();    // full vm+lgkm drain: buf0 ready, fA1 landed

    for (int ks = 0; ks < NS; ks += 2) {
        {   // i = ks (even): compute buf0; prefetch f32 tile i+2 -> fA0; cvtwrite tile i+1 from fA1
            const int i = ks;
            if (i + 2 < NS) loadA(fA0, (i + 2) * 32);
            WAIT_LGKM0();
            hard_barrier();   // barrier1
            if (i + 1 < NS) {
                stageB(1, (i + 1) * 32);
                if (i + 2 < NS) { WAIT_VMCNT(6); } else { WAIT_VMCNT(2); }
                cvtwrite(1, fA1);
            } else {
                WAIT_VMCNT(0);
            }
            hard_barrier();   // barrier2

            bf16x8 afr[4], bfr[4];
#pragma unroll
            for (int mi = 0; mi < 4; mi++)
                afr[mi] = *(const bf16x8*)&As[0][wr * 64 + mi * 16 + l15][gswB];
#pragma unroll
            for (int ni = 0; ni < 4; ni++)
                bfr[ni] = *(const bf16x8*)&Bs[0][wc * 64 + ni * 16 + l15][gswB];
#pragma unroll
            for (int mi = 0; mi < 4; mi++)
#pragma unroll
                for (int ni = 0; ni < 4; ni++)
                    acc[mi][ni] = __builtin_amdgcn_mfma_f32_16x16x32_bf16(
                        afr[mi], bfr[ni], acc[mi][ni], 0, 0, 0);
        }
        {   // i = ks+1 (odd): compute buf1; prefetch tile i+2 -> fA1; cvtwrite tile i+1 from fA0
            const int i = ks + 1;
            if (i + 2 < NS) loadA(fA1, (i + 2) * 32);
            WAIT_LGKM0();
            hard_barrier();   // barrier1
            if (i + 1 < NS) {
                stageB(0, (i + 1) * 32);
                if (i + 2 < NS) { WAIT_VMCNT(6); } else { WAIT_VMCNT(2); }
                cvtwrite(0, fA0);
            } else {
                WAIT_VMCNT(0);
            }
            hard_barrier();   // barrier2

            bf16x8 afr[4], bfr[4];
#pragma unroll
            for (int mi = 0; mi < 4; mi++)
                afr[mi] = *(const bf16x8*)&As[1][wr * 64 + mi * 16 + l15][gswB];
#pragma unroll
            for (int ni = 0; ni < 4; ni++)
                bfr[ni] = *(const bf16x8*)&Bs[1][wc * 64 + ni * 16 + l15][gswB];
#pragma unroll
            for (int mi = 0; mi < 4; mi++)
#pragma unroll
                for (int ni = 0; ni < 4; ni++)
                    acc[mi][ni] = __builtin_amdgcn_mfma_f32_16x16x32_bf16(
                        afr[mi], bfr[ni], acc[mi][ni], 0, 0, 0);
        }
    }

    // compacted destination slots (z>=1 only)
    int dts[4][4];
    if (z != 0) {
#pragma unroll
        for (int mi = 0; mi < 4; mi++) {
            const int r0 = bm + wr * 64 + mi * 16 + l16 * 4;
#pragma unroll
            for (int r = 0; r < 4; r++) dts[mi][r] = dtok[r0 + r];
        }
    }

#pragma unroll
    for (int ni = 0; ni < 4; ni++) {
        const int col = bn + wc * 64 + ni * 16 + l15;
        const float bv2 = bias[col];
#pragma unroll
        for (int mi = 0; mi < 4; mi++) {
            const int r0 = bm + wr * 64 + mi * 16 + l16 * 4;
            const int bb = r0 >> 11;
            if (z == 0) {
#pragma unroll
                for (int r = 0; r < 4; r++)
                    Cq[(size_t)(r0 + r) * N + col] = f2bf(acc[mi][ni][r] + bv2);
            } else if (z == 1) {
#pragma unroll
                for (int r = 0; r < 4; r++) {
                    const int d = dts[mi][r];
                    if (d >= 0)
                        Ck[((size_t)(bb * 2048 + d)) * 1024 + col] =
                            f2bf(acc[mi][ni][r] + bv2);
                    else if (d != -1)
                        Ck[((size_t)(bb * 2048 + (-d - 2))) * 1024 + col] = 0;
                }
            } else {
                const int hh = col >> 6, dk = col & 63;
                u16* dst = Cvp + (((size_t)(bb * 16 + hh) * 64 + dk) << 11);
#pragma unroll
                for (int r = 0; r < 4; r++) {
                    const int d = dts[mi][r];
                    if (d >= 0) dst[d] = f2bf(acc[mi][ni][r] + bv2);
                    else if (d != -1) dst[-d - 2] = 0;
                }
            }
        }
    }
}

// ---------------- out-projection GEMM (f32 out), swizzled LDS — R19/R20 proven ----------------
__global__ __launch_bounds__(256) void gemm_out(const u16* __restrict__ A,
                                                const u16* __restrict__ B,
                                                const float* __restrict__ bias,
                                                float* __restrict__ Cv,
                                                int M, int N, int K) {
    __shared__ __align__(16) u16 As[2][128][32];
    __shared__ __align__(16) u16 Bs[2][128][32];
    const int t = threadIdx.x, lane = t & 63, w = t >> 6;
    const int wr = w >> 1, wc = w & 1;
    const int l15 = lane & 15, l16 = lane >> 4;
    const int nwg = gridDim.x, ntiles = N >> 7;
    const int wg = blockIdx.x, chunk = nwg >> 3;
    const int swz = (wg & 7) * chunk + (wg >> 3);
    const int bm = (swz / ntiles) * 128, bn = (swz % ntiles) * 128;
    const int srow = w * 16 + (lane >> 2);
    const int sgrB = ((lane & 3) ^ ((lane >> 3) & 3)) * 8;
    const int gswB = (l16 ^ ((l15 >> 1) & 3)) * 8;
    const u16* Ab = A + (size_t)bm * K;
    const u16* Bb = B + (size_t)bn * K;

    f32x4 acc[4][4];
#pragma unroll
    for (int i = 0; i < 4; i++)
#pragma unroll
        for (int j = 0; j < 4; j++) acc[i][j] = (f32x4){0.f, 0.f, 0.f, 0.f};

    auto stage = [&](int c, int k0) {
        gload16(Ab + (size_t)srow * K + k0 + sgrB,        &As[c][w * 16][0]);
        gload16(Ab + (size_t)(64 + srow) * K + k0 + sgrB, &As[c][64 + w * 16][0]);
        gload16(Bb + (size_t)srow * K + k0 + sgrB,        &Bs[c][w * 16][0]);
        gload16(Bb + (size_t)(64 + srow) * K + k0 + sgrB, &Bs[c][64 + w * 16][0]);
    };

    stage(0, 0);
    __syncthreads();

    const int NS = K >> 5;
    for (int i = 0; i < NS; ++i) {
        const int c = i & 1;
        WAIT_LGKM0();
        hard_barrier();
        if (i + 1 < NS) {
            stage(c ^ 1, (i + 1) * 32);
            WAIT_VMCNT(4);
        } else {
            WAIT_VMCNT(0);
        }
        hard_barrier();

        bf16x8 afr[4], bfr[4];
#pragma unroll
        for (int mi = 0; mi < 4; mi++)
            afr[mi] = *(const bf16x8*)&As[c][wr * 64 + mi * 16 + l15][gswB];
#pragma unroll
        for (int ni = 0; ni < 4; ni++)
            bfr[ni] = *(const bf16x8*)&Bs[c][wc * 64 + ni * 16 + l15][gswB];
#pragma unroll
        for (int mi = 0; mi < 4; mi++)
#pragma unroll
            for (int ni = 0; ni < 4; ni++)
                acc[mi][ni] = __builtin_amdgcn_mfma_f32_16x16x32_bf16(
                    afr[mi], bfr[ni], acc[mi][ni], 0, 0, 0);
    }

#pragma unroll
    for (int ni = 0; ni < 4; ni++) {
        const int col = bn + wc * 64 + ni * 16 + l15;
        const float bv = bias[col];
#pragma unroll
        for (int mi = 0; mi < 4; mi++) {
            const int r0 = bm + wr * 64 + mi * 16 + l16 * 4;
#pragma unroll
            for (int r = 0; r < 4; r++)
                Cv[(size_t)(r0 + r) * N + col] = acc[mi][ni][r] + bv;
        }
    }
}

// ---------------- flash attention over COMPACTED keys — EXACT R19/R20 version ----------------
__global__ __launch_bounds__(256, 2) void attn_fwd(const u16* __restrict__ Q,
                                                   const u16* __restrict__ Kg,
                                                   const u16* __restrict__ Vt,
                                                   const int* __restrict__ NbA,
                                                   u16* __restrict__ O) {
    constexpr int S = 2048, D = 1024;
    __shared__ __align__(16) u16 Kl[2][2][2][64][32];
    __shared__ __align__(16) u16 Vl[2][2][2][64][32];
    __shared__ __align__(16) u16 Pl[4][16][68];
    __shared__ __align__(16) u16 Ml[2048];
    const int t = threadIdx.x, lane = t & 63, w = t >> 6;
    const int l15 = lane & 15, l16 = lane >> 4;
    const int wg = blockIdx.x;
    const int swz = (wg & 7) * 64 + (wg >> 3);
    const int q0 = (swz & 7) * 256, hd = (swz >> 3) & 15, b = swz >> 7;
    const int qb = q0 + w * 64;
    const int srow = w * 16 + (lane >> 2);
    const int sgr = ((lane & 3) ^ ((lane >> 3) & 3)) * 8;
    const int gsw8 = (l16 ^ ((l15 >> 1) & 3)) * 8;

    const int Nb = NbA[b];
    const int nt = (Nb + 127) >> 7;

    const u16* Khead = Kg + (size_t)b * S * D;
    const u16* Vthead = Vt + (size_t)(b * 16 + hd) * 64 * 2048;

    auto stage = [&](int c, int kt) {
#pragma unroll
        for (int kg = 0; kg < 2; kg++) {
            const int k0 = kt + kg * 64;
            gload16(Khead + (size_t)(k0 + srow) * D + hd * 64 + sgr,      &Kl[c][kg][0][w * 16][0]);
            gload16(Khead + (size_t)(k0 + srow) * D + hd * 64 + 32 + sgr, &Kl[c][kg][1][w * 16][0]);
            gload16(Vthead + (size_t)srow * 2048 + k0 + sgr,              &Vl[c][kg][0][w * 16][0]);
            gload16(Vthead + (size_t)srow * 2048 + k0 + 32 + sgr,         &Vl[c][kg][1][w * 16][0]);
        }
    };

    stage(0, 0);
    {
        u16x8 mv;
#pragma unroll
        for (int j = 0; j < 8; j++) mv[j] = (t * 8 + j < Nb) ? (u16)0x3F80 : (u16)0;
        *(u16x8*)&Ml[t * 8] = mv;
    }

    constexpr float QSCALE = 0.125f * 1.44269504f;
    bf16x8 aq[4][2];
#pragma unroll
    for (int qt = 0; qt < 4; qt++)
#pragma unroll
        for (int ks = 0; ks < 2; ks++) {
            const size_t qi = ((size_t)b * S + qb + qt * 16 + l15) * D +
                              hd * 64 + ks * 32 + l16 * 8;
            u16x8 raw = *(const u16x8*)&Q[qi];
            bf16x8 qv;
#pragma unroll
            for (int i = 0; i < 8; i++) qv[i] = (__bf16)(bf2f(raw[i]) * QSCALE);
            aq[qt][ks] = qv;
        }

    f32x4 acc[4][4];
    f32x4 accl[4];
#pragma unroll
    for (int qt = 0; qt < 4; qt++) {
        accl[qt] = (f32x4){0.f, 0.f, 0.f, 0.f};
#pragma unroll
        for (int dt = 0; dt < 4; dt++) acc[qt][dt] = (f32x4){0.f, 0.f, 0.f, 0.f};
    }

    __syncthreads();

    for (int tile = 0; tile < nt; ++tile) {
        const int c = tile & 1;
        const int cur = tile * 128;
        WAIT_LGKM0();
        hard_barrier();
        if (tile + 1 < nt) {
            stage(c ^ 1, cur + 128);
            WAIT_VMCNT(8);
        } else {
            WAIT_VMCNT(0);
        }
        hard_barrier();

#pragma unroll
        for (int kg = 0; kg < 2; kg++) {
            bf16x8 kf0[4], kf1[4], vf0[4], vf1[4];
#pragma unroll
            for (int k4 = 0; k4 < 4; k4++) {
                kf0[k4] = *(const bf16x8*)&Kl[c][kg][0][k4 * 16 + l15][gsw8];
                kf1[k4] = *(const bf16x8*)&Kl[c][kg][1][k4 * 16 + l15][gsw8];
            }
#pragma unroll
            for (int dt = 0; dt < 4; dt++) {
                vf0[dt] = *(const bf16x8*)&Vl[c][kg][0][dt * 16 + l15][gsw8];
                vf1[dt] = *(const bf16x8*)&Vl[c][kg][1][dt * 16 + l15][gsw8];
            }
            const int kbase = cur + kg * 64;
            bf16x8 mv0 = *(const bf16x8*)&Ml[kbase + l16 * 8];
            bf16x8 mv1 = *(const bf16x8*)&Ml[kbase + 32 + l16 * 8];

#pragma unroll
            for (int qt = 0; qt < 4; qt++) {
#pragma unroll
                for (int k4 = 0; k4 < 4; k4++) {
                    f32x4 z = (f32x4){0.f, 0.f, 0.f, 0.f};
                    z = __builtin_amdgcn_mfma_f32_16x16x32_bf16(kf0[k4], aq[qt][0], z, 0, 0, 0);
                    z = __builtin_amdgcn_mfma_f32_16x16x32_bf16(kf1[k4], aq[qt][1], z, 0, 0, 0);
                    u16x4 pk;
#pragma unroll
                    for (int r = 0; r < 4; r++)
                        pk[r] = f2bf(__builtin_amdgcn_exp2f(z[r]));
                    *(u16x4*)&Pl[w][l15][k4 * 16 + l16 * 4] = pk;
                }
                bf16x8 pa0 = *(const bf16x8*)&Pl[w][l15][l16 * 8];
                bf16x8 pa1 = *(const bf16x8*)&Pl[w][l15][32 + l16 * 8];
                accl[qt] = __builtin_amdgcn_mfma_f32_16x16x32_bf16(pa0, mv0, accl[qt], 0, 0, 0);
                accl[qt] = __builtin_amdgcn_mfma_f32_16x16x32_bf16(pa1, mv1, accl[qt], 0, 0, 0);
#pragma unroll
                for (int dt = 0; dt < 4; dt++) {
                    acc[qt][dt] = __builtin_amdgcn_mfma_f32_16x16x32_bf16(
                        pa0, vf0[dt], acc[qt][dt], 0, 0, 0);
                    acc[qt][dt] = __builtin_amdgcn_mfma_f32_16x16x32_bf16(
                        pa1, vf1[dt], acc[qt][dt], 0, 0, 0);
                }
            }
        }
    }

#pragma unroll
    for (int qt = 0; qt < 4; qt++) {
        f32x4 inv;
#pragma unroll
        for (int r = 0; r < 4; r++) inv[r] = 1.f / accl[qt][r];
#pragma unroll
        for (int dt = 0; dt < 4; dt++)
#pragma unroll
            for (int r = 0; r < 4; r++) {
                const int tok = qb + qt * 16 + l16 * 4 + r;
                O[((size_t)b * S + tok) * D + hd * 64 + dt * 16 + l15] =
                    f2bf(acc[qt][dt][r] * inv[r]);
            }
    }
}

extern "C" void kernel_launch(void* const* d_in, const int* in_sizes, int n_in,
                              void* d_out, int out_size, void* d_ws, size_t ws_size,
                              hipStream_t stream) {
    const float* query = (const float*)d_in[0];
    const float* key   = (const float*)d_in[1];
    const float* value = (const float*)d_in[2];
    const int*   mask  = (const int*)d_in[3];
    const float* Wq = (const float*)d_in[4];
    const float* bq = (const float*)d_in[5];
    const float* Wk = (const float*)d_in[6];
    const float* bk = (const float*)d_in[7];
    const float* Wv = (const float*)d_in[8];
    const float* bv = (const float*)d_in[9];
    const float* Wo = (const float*)d_in[10];
    const float* bo = (const float*)d_in[11];
    float* out = (float*)d_out;

    constexpr int S = 2048, D = 1024;
    constexpr size_t MSZ = (size_t)4 * S * D;   // 8388608
    constexpr size_t WSZ = (size_t)D * D;       // 1048576
    const size_t need = 4 * WSZ * 2 + 2 * MSZ * 2 + 8192 * 4 + 64;
    if (ws_size < need) return;

    char* p = (char*)d_ws;
    u16* Wqb = (u16*)p; p += WSZ * 2;
    u16* Wkb = (u16*)p; p += WSZ * 2;
    u16* Wvb = (u16*)p; p += WSZ * 2;
    u16* Wob = (u16*)p; p += WSZ * 2;
    u16* Xb  = (u16*)p; p += MSZ * 2;
    u16* Qb  = (u16*)p; p += MSZ * 2;
    int* dtok = (int*)p; p += 8192 * 4;
    int* NbA = (int*)p; p += 64;
    u16* Kc  = (u16*)d_out;
    u16* Vtc = (u16*)d_out + MSZ;

    cvt4<<<dim3(WSZ / 1024, 4), 256, 0, stream>>>(Wq, Wk, Wv, Wo,
                                                  Wqb, Wkb, Wvb, Wob, (int)WSZ);
    build_dtok<<<4, 256, 0, stream>>>(mask, dtok, NbA);
    gemm_qkv<<<dim3(512, 1, 3), 256, 0, stream>>>(query, key, value,
                                                  Wqb, Wkb, Wvb, bq, bk, bv, dtok,
                                                  Qb, Kc, Vtc, 8192, 1024, 1024);
    attn_fwd<<<512, 256, 0, stream>>>(Qb, Kc, Vtc, NbA, Xb);
    gemm_out<<<512, 256, 0, stream>>>(Xb, Wob, bo, out, 8192, 1024, 1024);
}

// Round 22
// 178.730 us; speedup vs baseline: 1.1154x; 1.1154x over previous
//
#include <hip/hip_runtime.h>

typedef unsigned short u16;
typedef unsigned int u32;
typedef __bf16 bf16x8 __attribute__((ext_vector_type(8)));
typedef float f32x4 __attribute__((ext_vector_type(4)));
typedef u16 u16x8 __attribute__((ext_vector_type(8)));
typedef u16 u16x4 __attribute__((ext_vector_type(4)));

typedef __attribute__((address_space(1))) const unsigned char gc_u8;
typedef __attribute__((address_space(3))) unsigned char lds_u8;

__device__ inline void gload16(const void* g, void* l) {
    __builtin_amdgcn_global_load_lds((gc_u8*)g, (lds_u8*)l, 16, 0, 0);
}
__device__ inline u16 f2bf(float f) {
    union { __bf16 h; u16 u; } c; c.h = (__bf16)f; return c.u;
}
__device__ inline float bf2f(u16 u) {
    union { u16 u[2]; float f; } c; c.u[0] = 0; c.u[1] = u; return c.f;
}
__device__ inline void hard_barrier() {
    __builtin_amdgcn_sched_barrier(0);
    __builtin_amdgcn_s_barrier();
    __builtin_amdgcn_sched_barrier(0);
}
#define WAIT_LGKM0() asm volatile("s_waitcnt lgkmcnt(0)" ::: "memory")
#define WAIT_VMCNT(n) asm volatile("s_waitcnt vmcnt(" #n ")" ::: "memory")

// ---------------- weight fp32 -> bf16 convert ----------------
__global__ __launch_bounds__(256) void cvt4(const float* __restrict__ s0,
                                            const float* __restrict__ s1,
                                            const float* __restrict__ s2,
                                            const float* __restrict__ s3,
                                            u16* __restrict__ d0, u16* __restrict__ d1,
                                            u16* __restrict__ d2, u16* __restrict__ d3,
                                            int n) {
    const int y = blockIdx.y;
    const float* src = (y == 0) ? s0 : (y == 1) ? s1 : (y == 2) ? s2 : s3;
    u16* dst = (y == 0) ? d0 : (y == 1) ? d1 : (y == 2) ? d2 : d3;
    int i = (blockIdx.x * 256 + threadIdx.x) * 4;
    if (i < n) {
        float4 f = *reinterpret_cast<const float4*>(src + i);
        u16x4 u = { f2bf(f.x), f2bf(f.y), f2bf(f.z), f2bf(f.w) };
        *reinterpret_cast<u16x4*>(dst + i) = u;
    }
}

// ---------------- per-token compacted destination index (order-preserving) ----------------
// dtok[b*2048+s]: unmasked -> d (#unmasked before s); masked with pad-slot
// Nb + rank_masked(s) < pad -> -(slot+2) (epilogue writes ZEROS there); else -1.
__global__ __launch_bounds__(256) void build_dtok(const int* __restrict__ mask,
                                                  int* __restrict__ dtok,
                                                  int* __restrict__ NbA) {
    __shared__ u32 W[64];
    __shared__ u32 Wpre[65];
    const int b = blockIdx.x, t = threadIdx.x;
    const int* mrow = mask + b * 2048;
    if (t < 64) {
        u32 wv = 0;
#pragma unroll 8
        for (int j = 0; j < 32; j++) wv |= (mrow[t * 32 + j] ? 1u : 0u) << j;
        W[t] = wv;
    }
    __syncthreads();
    if (t == 0) {
        u32 s = 0;
        for (int i = 0; i < 64; i++) { Wpre[i] = s; s += __popc(W[i]); }
        Wpre[64] = s;
        NbA[b] = (int)s;
    }
    __syncthreads();
    const int Nb = (int)Wpre[64];
    const int pad = (Nb + 127) & ~127;
#pragma unroll
    for (int i = 0; i < 8; i++) {
        const int s = t * 8 + i;
        const u32 word = W[s >> 5];
        const int pre = (int)Wpre[s >> 5] + __popc(word & ((1u << (s & 31)) - 1u));
        int v;
        if ((word >> (s & 31)) & 1u) {
            v = pre;
        } else {
            const int slot = Nb + (s - pre);
            v = (slot < pad) ? -(slot + 2) : -1;
        }
        dtok[b * 2048 + s] = v;
    }
}

// ---------------- merged QKV projection GEMM, f32-A via gload_lds, COMPACTING epilogue ----------------
// R19-exact (measured best). A staged as f32 DMA into XOR-swizzled LDS, converted
// at fragment-load; Bs swizzled. z==0: Q. z==1: K compacted. z==2: V^T compacted.
__global__ __launch_bounds__(256) void gemm_qkv(const float* __restrict__ Aq,
                                                const float* __restrict__ Ak,
                                                const float* __restrict__ Av,
                                                const u16* __restrict__ Bq,
                                                const u16* __restrict__ Bk,
                                                const u16* __restrict__ Bv,
                                                const float* __restrict__ bq,
                                                const float* __restrict__ bk,
                                                const float* __restrict__ bv,
                                                const int* __restrict__ dtok,
                                                u16* __restrict__ Cq,
                                                u16* __restrict__ Ck,
                                                u16* __restrict__ Cvp,
                                                int M, int N, int K) {
    __shared__ __align__(16) float Asf[2][128][32];
    __shared__ __align__(16) u16 Bs[2][128][32];
    const int z = blockIdx.z;
    const float* A = (z == 0) ? Aq : (z == 1) ? Ak : Av;
    const u16* B = (z == 0) ? Bq : (z == 1) ? Bk : Bv;
    const float* bias = (z == 0) ? bq : (z == 1) ? bk : bv;

    const int t = threadIdx.x, lane = t & 63, w = t >> 6;
    const int wr = w >> 1, wc = w & 1;
    const int l15 = lane & 15, l16 = lane >> 4;
    const int nwg = gridDim.x, ntiles = N >> 7;
    const int wg = blockIdx.x, chunk = nwg >> 3;
    const int swz = (wg & 7) * chunk + (wg >> 3);
    const int bm = (swz / ntiles) * 128, bn = (swz % ntiles) * 128;
    const int srow = w * 16 + (lane >> 2);
    const int sgrB = ((lane & 3) ^ ((lane >> 3) & 3)) * 8;  // swizzled bf16 source granule
    const int gswB = (l16 ^ ((l15 >> 1) & 3)) * 8;          // swizzled bf16 read granule
    const int arsub = lane >> 3;
    const int agr = ((lane & 7) ^ (lane >> 3)) * 4;         // f32 source granule
    const u16* Bb = B + (size_t)bn * K;

    f32x4 acc[4][4];
#pragma unroll
    for (int i = 0; i < 4; i++)
#pragma unroll
        for (int j = 0; j < 4; j++) acc[i][j] = (f32x4){0.f, 0.f, 0.f, 0.f};

    auto stage = [&](int c, int k0) {
#pragma unroll
        for (int ch = 0; ch < 4; ch++)
            gload16(A + (size_t)(bm + ch * 32 + w * 8 + arsub) * K + k0 + agr,
                    &Asf[c][ch * 32 + w * 8][0]);
        gload16(Bb + (size_t)srow * K + k0 + sgrB,        &Bs[c][w * 16][0]);
        gload16(Bb + (size_t)(64 + srow) * K + k0 + sgrB, &Bs[c][64 + w * 16][0]);
    };

    stage(0, 0);
    __syncthreads();

    const int NS = K >> 5;
    for (int i = 0; i < NS; ++i) {
        const int c = i & 1;
        WAIT_LGKM0();
        hard_barrier();
        if (i + 1 < NS) {
            stage(c ^ 1, (i + 1) * 32);
            WAIT_VMCNT(6);
        } else {
            WAIT_VMCNT(0);
        }
        hard_barrier();

        const int key = l15 & 7;
        bf16x8 afr[4], bfr[4];
#pragma unroll
        for (int mi = 0; mi < 4; mi++) {
            const int rr = wr * 64 + mi * 16 + l15;
            f32x4 lo = *(const f32x4*)&Asf[c][rr][((2 * l16) ^ key) * 4];
            f32x4 hi = *(const f32x4*)&Asf[c][rr][((2 * l16 + 1) ^ key) * 4];
            bf16x8 v;
            v[0] = (__bf16)lo[0]; v[1] = (__bf16)lo[1];
            v[2] = (__bf16)lo[2]; v[3] = (__bf16)lo[3];
            v[4] = (__bf16)hi[0]; v[5] = (__bf16)hi[1];
            v[6] = (__bf16)hi[2]; v[7] = (__bf16)hi[3];
            afr[mi] = v;
        }
#pragma unroll
        for (int ni = 0; ni < 4; ni++)
            bfr[ni] = *(const bf16x8*)&Bs[c][wc * 64 + ni * 16 + l15][gswB];
#pragma unroll
        for (int mi = 0; mi < 4; mi++)
#pragma unroll
            for (int ni = 0; ni < 4; ni++)
                acc[mi][ni] = __builtin_amdgcn_mfma_f32_16x16x32_bf16(
                    afr[mi], bfr[ni], acc[mi][ni], 0, 0, 0);
    }

    // compacted destination slots for this thread's 16 tokens (z>=1 only)
    int dts[4][4];
    if (z != 0) {
#pragma unroll
        for (int mi = 0; mi < 4; mi++) {
            const int r0 = bm + wr * 64 + mi * 16 + l16 * 4;
#pragma unroll
            for (int r = 0; r < 4; r++) dts[mi][r] = dtok[r0 + r];
        }
    }

#pragma unroll
    for (int ni = 0; ni < 4; ni++) {
        const int col = bn + wc * 64 + ni * 16 + l15;
        const float bv2 = bias[col];
#pragma unroll
        for (int mi = 0; mi < 4; mi++) {
            const int r0 = bm + wr * 64 + mi * 16 + l16 * 4;
            const int bb = r0 >> 11;
            if (z == 0) {
#pragma unroll
                for (int r = 0; r < 4; r++)
                    Cq[(size_t)(r0 + r) * N + col] = f2bf(acc[mi][ni][r] + bv2);
            } else if (z == 1) {  // K compacted rows (+ pad-zero duty)
#pragma unroll
                for (int r = 0; r < 4; r++) {
                    const int d = dts[mi][r];
                    if (d >= 0)
                        Ck[((size_t)(bb * 2048 + d)) * 1024 + col] =
                            f2bf(acc[mi][ni][r] + bv2);
                    else if (d != -1)
                        Ck[((size_t)(bb * 2048 + (-d - 2))) * 1024 + col] = 0;
                }
            } else {  // V^T compacted (b,h,dk,d) (+ pad-zero duty)
                const int hh = col >> 6, dk = col & 63;
                u16* dst = Cvp + (((size_t)(bb * 16 + hh) * 64 + dk) << 11);
#pragma unroll
                for (int r = 0; r < 4; r++) {
                    const int d = dts[mi][r];
                    if (d >= 0) dst[d] = f2bf(acc[mi][ni][r] + bv2);
                    else if (d != -1) dst[-d - 2] = 0;
                }
            }
        }
    }
}

// ---------------- out-projection GEMM (f32 out), swizzled LDS — R19 proven ----------------
__global__ __launch_bounds__(256) void gemm_out(const u16* __restrict__ A,
                                                const u16* __restrict__ B,
                                                const float* __restrict__ bias,
                                                float* __restrict__ Cv,
                                                int M, int N, int K) {
    __shared__ __align__(16) u16 As[2][128][32];
    __shared__ __align__(16) u16 Bs[2][128][32];
    const int t = threadIdx.x, lane = t & 63, w = t >> 6;
    const int wr = w >> 1, wc = w & 1;
    const int l15 = lane & 15, l16 = lane >> 4;
    const int nwg = gridDim.x, ntiles = N >> 7;
    const int wg = blockIdx.x, chunk = nwg >> 3;
    const int swz = (wg & 7) * chunk + (wg >> 3);
    const int bm = (swz / ntiles) * 128, bn = (swz % ntiles) * 128;
    const int srow = w * 16 + (lane >> 2);
    const int sgrB = ((lane & 3) ^ ((lane >> 3) & 3)) * 8;
    const int gswB = (l16 ^ ((l15 >> 1) & 3)) * 8;
    const u16* Ab = A + (size_t)bm * K;
    const u16* Bb = B + (size_t)bn * K;

    f32x4 acc[4][4];
#pragma unroll
    for (int i = 0; i < 4; i++)
#pragma unroll
        for (int j = 0; j < 4; j++) acc[i][j] = (f32x4){0.f, 0.f, 0.f, 0.f};

    auto stage = [&](int c, int k0) {
        gload16(Ab + (size_t)srow * K + k0 + sgrB,        &As[c][w * 16][0]);
        gload16(Ab + (size_t)(64 + srow) * K + k0 + sgrB, &As[c][64 + w * 16][0]);
        gload16(Bb + (size_t)srow * K + k0 + sgrB,        &Bs[c][w * 16][0]);
        gload16(Bb + (size_t)(64 + srow) * K + k0 + sgrB, &Bs[c][64 + w * 16][0]);
    };

    stage(0, 0);
    __syncthreads();

    const int NS = K >> 5;
    for (int i = 0; i < NS; ++i) {
        const int c = i & 1;
        WAIT_LGKM0();
        hard_barrier();
        if (i + 1 < NS) {
            stage(c ^ 1, (i + 1) * 32);
            WAIT_VMCNT(4);
        } else {
            WAIT_VMCNT(0);
        }
        hard_barrier();

        bf16x8 afr[4], bfr[4];
#pragma unroll
        for (int mi = 0; mi < 4; mi++)
            afr[mi] = *(const bf16x8*)&As[c][wr * 64 + mi * 16 + l15][gswB];
#pragma unroll
        for (int ni = 0; ni < 4; ni++)
            bfr[ni] = *(const bf16x8*)&Bs[c][wc * 64 + ni * 16 + l15][gswB];
#pragma unroll
        for (int mi = 0; mi < 4; mi++)
#pragma unroll
            for (int ni = 0; ni < 4; ni++)
                acc[mi][ni] = __builtin_amdgcn_mfma_f32_16x16x32_bf16(
                    afr[mi], bfr[ni], acc[mi][ni], 0, 0, 0);
    }

#pragma unroll
    for (int ni = 0; ni < 4; ni++) {
        const int col = bn + wc * 64 + ni * 16 + l15;
        const float bv = bias[col];
#pragma unroll
        for (int mi = 0; mi < 4; mi++) {
            const int r0 = bm + wr * 64 + mi * 16 + l16 * 4;
#pragma unroll
            for (int r = 0; r < 4; r++)
                Cv[(size_t)(r0 + r) * N + col] = acc[mi][ni][r] + bv;
        }
    }
}

// ---------------- flash attention over COMPACTED keys — R19 proven ----------------
__global__ __launch_bounds__(256, 2) void attn_fwd(const u16* __restrict__ Q,
                                                   const u16* __restrict__ Kg,
                                                   const u16* __restrict__ Vt,
                                                   const int* __restrict__ NbA,
                                                   u16* __restrict__ O) {
    constexpr int S = 2048, D = 1024;
    __shared__ __align__(16) u16 Kl[2][2][2][64][32];
    __shared__ __align__(16) u16 Vl[2][2][2][64][32];
    __shared__ __align__(16) u16 Pl[4][16][68];
    __shared__ __align__(16) u16 Ml[2048];
    const int t = threadIdx.x, lane = t & 63, w = t >> 6;
    const int l15 = lane & 15, l16 = lane >> 4;
    const int wg = blockIdx.x;
    const int swz = (wg & 7) * 64 + (wg >> 3);
    const int q0 = (swz & 7) * 256, hd = (swz >> 3) & 15, b = swz >> 7;
    const int qb = q0 + w * 64;
    const int srow = w * 16 + (lane >> 2);
    const int sgr = ((lane & 3) ^ ((lane >> 3) & 3)) * 8;
    const int gsw8 = (l16 ^ ((l15 >> 1) & 3)) * 8;

    const int Nb = NbA[b];
    const int nt = (Nb + 127) >> 7;

    const u16* Khead = Kg + (size_t)b * S * D;
    const u16* Vthead = Vt + (size_t)(b * 16 + hd) * 64 * 2048;

    auto stage = [&](int c, int kt) {
#pragma unroll
        for (int kg = 0; kg < 2; kg++) {
            const int k0 = kt + kg * 64;
            gload16(Khead + (size_t)(k0 + srow) * D + hd * 64 + sgr,      &Kl[c][kg][0][w * 16][0]);
            gload16(Khead + (size_t)(k0 + srow) * D + hd * 64 + 32 + sgr, &Kl[c][kg][1][w * 16][0]);
            gload16(Vthead + (size_t)srow * 2048 + k0 + sgr,              &Vl[c][kg][0][w * 16][0]);
            gload16(Vthead + (size_t)srow * 2048 + k0 + 32 + sgr,         &Vl[c][kg][1][w * 16][0]);
        }
    };

    stage(0, 0);
    {
        u16x8 mv;
#pragma unroll
        for (int j = 0; j < 8; j++) mv[j] = (t * 8 + j < Nb) ? (u16)0x3F80 : (u16)0;
        *(u16x8*)&Ml[t * 8] = mv;
    }

    constexpr float QSCALE = 0.125f * 1.44269504f;
    bf16x8 aq[4][2];
#pragma unroll
    for (int qt = 0; qt < 4; qt++)
#pragma unroll
        for (int ks = 0; ks < 2; ks++) {
            const size_t qi = ((size_t)b * S + qb + qt * 16 + l15) * D +
                              hd * 64 + ks * 32 + l16 * 8;
            u16x8 raw = *(const u16x8*)&Q[qi];
            bf16x8 qv;
#pragma unroll
            for (int i = 0; i < 8; i++) qv[i] = (__bf16)(bf2f(raw[i]) * QSCALE);
            aq[qt][ks] = qv;
        }

    f32x4 acc[4][4];
    f32x4 accl[4];
#pragma unroll
    for (int qt = 0; qt < 4; qt++) {
        accl[qt] = (f32x4){0.f, 0.f, 0.f, 0.f};
#pragma unroll
        for (int dt = 0; dt < 4; dt++) acc[qt][dt] = (f32x4){0.f, 0.f, 0.f, 0.f};
    }

    __syncthreads();

    for (int tile = 0; tile < nt; ++tile) {
        const int c = tile & 1;
        const int cur = tile * 128;
        WAIT_LGKM0();
        hard_barrier();
        if (tile + 1 < nt) {
            stage(c ^ 1, cur + 128);
            WAIT_VMCNT(8);
        } else {
            WAIT_VMCNT(0);
        }
        hard_barrier();

#pragma unroll
        for (int kg = 0; kg < 2; kg++) {
            bf16x8 kf0[4], kf1[4], vf0[4], vf1[4];
#pragma unroll
            for (int k4 = 0; k4 < 4; k4++) {
                kf0[k4] = *(const bf16x8*)&Kl[c][kg][0][k4 * 16 + l15][gsw8];
                kf1[k4] = *(const bf16x8*)&Kl[c][kg][1][k4 * 16 + l15][gsw8];
            }
#pragma unroll
            for (int dt = 0; dt < 4; dt++) {
                vf0[dt] = *(const bf16x8*)&Vl[c][kg][0][dt * 16 + l15][gsw8];
                vf1[dt] = *(const bf16x8*)&Vl[c][kg][1][dt * 16 + l15][gsw8];
            }
            const int kbase = cur + kg * 64;
            bf16x8 mv0 = *(const bf16x8*)&Ml[kbase + l16 * 8];
            bf16x8 mv1 = *(const bf16x8*)&Ml[kbase + 32 + l16 * 8];

#pragma unroll
            for (int qt = 0; qt < 4; qt++) {
#pragma unroll
                for (int k4 = 0; k4 < 4; k4++) {
                    f32x4 z = (f32x4){0.f, 0.f, 0.f, 0.f};
                    z = __builtin_amdgcn_mfma_f32_16x16x32_bf16(kf0[k4], aq[qt][0], z, 0, 0, 0);
                    z = __builtin_amdgcn_mfma_f32_16x16x32_bf16(kf1[k4], aq[qt][1], z, 0, 0, 0);
                    u16x4 pk;
#pragma unroll
                    for (int r = 0; r < 4; r++)
                        pk[r] = f2bf(__builtin_amdgcn_exp2f(z[r]));
                    *(u16x4*)&Pl[w][l15][k4 * 16 + l16 * 4] = pk;
                }
                bf16x8 pa0 = *(const bf16x8*)&Pl[w][l15][l16 * 8];
                bf16x8 pa1 = *(const bf16x8*)&Pl[w][l15][32 + l16 * 8];
                accl[qt] = __builtin_amdgcn_mfma_f32_16x16x32_bf16(pa0, mv0, accl[qt], 0, 0, 0);
                accl[qt] = __builtin_amdgcn_mfma_f32_16x16x32_bf16(pa1, mv1, accl[qt], 0, 0, 0);
#pragma unroll
                for (int dt = 0; dt < 4; dt++) {
                    acc[qt][dt] = __builtin_amdgcn_mfma_f32_16x16x32_bf16(
                        pa0, vf0[dt], acc[qt][dt], 0, 0, 0);
                    acc[qt][dt] = __builtin_amdgcn_mfma_f32_16x16x32_bf16(
                        pa1, vf1[dt], acc[qt][dt], 0, 0, 0);
                }
            }
        }
    }

#pragma unroll
    for (int qt = 0; qt < 4; qt++) {
        f32x4 inv;
#pragma unroll
        for (int r = 0; r < 4; r++) inv[r] = 1.f / accl[qt][r];
#pragma unroll
        for (int dt = 0; dt < 4; dt++)
#pragma unroll
            for (int r = 0; r < 4; r++) {
                const int tok = qb + qt * 16 + l16 * 4 + r;
                O[((size_t)b * S + tok) * D + hd * 64 + dt * 16 + l15] =
                    f2bf(acc[qt][dt][r] * inv[r]);
            }
    }
}

extern "C" void kernel_launch(void* const* d_in, const int* in_sizes, int n_in,
                              void* d_out, int out_size, void* d_ws, size_t ws_size,
                              hipStream_t stream) {
    const float* query = (const float*)d_in[0];
    const float* key   = (const float*)d_in[1];
    const float* value = (const float*)d_in[2];
    const int*   mask  = (const int*)d_in[3];
    const float* Wq = (const float*)d_in[4];
    const float* bq = (const float*)d_in[5];
    const float* Wk = (const float*)d_in[6];
    const float* bk = (const float*)d_in[7];
    const float* Wv = (const float*)d_in[8];
    const float* bv = (const float*)d_in[9];
    const float* Wo = (const float*)d_in[10];
    const float* bo = (const float*)d_in[11];
    float* out = (float*)d_out;

    constexpr int S = 2048, D = 1024;
    constexpr size_t MSZ = (size_t)4 * S * D;   // 8388608
    constexpr size_t WSZ = (size_t)D * D;       // 1048576
    const size_t need = 4 * WSZ * 2 + 2 * MSZ * 2 + 8192 * 4 + 64;
    if (ws_size < need) return;

    char* p = (char*)d_ws;
    u16* Wqb = (u16*)p; p += WSZ * 2;
    u16* Wkb = (u16*)p; p += WSZ * 2;
    u16* Wvb = (u16*)p; p += WSZ * 2;
    u16* Wob = (u16*)p; p += WSZ * 2;
    u16* Xb  = (u16*)p; p += MSZ * 2;
    u16* Qb  = (u16*)p; p += MSZ * 2;
    int* dtok = (int*)p; p += 8192 * 4;
    int* NbA = (int*)p; p += 64;
    u16* Kc  = (u16*)d_out;            // compacted K rows (pad rows zeroed in-epilogue)
    u16* Vtc = (u16*)d_out + MSZ;      // compacted V^T (pad slots zeroed in-epilogue)

    cvt4<<<dim3(WSZ / 1024, 4), 256, 0, stream>>>(Wq, Wk, Wv, Wo,
                                                  Wqb, Wkb, Wvb, Wob, (int)WSZ);
    build_dtok<<<4, 256, 0, stream>>>(mask, dtok, NbA);
    gemm_qkv<<<dim3(512, 1, 3), 256, 0, stream>>>(query, key, value,
                                                  Wqb, Wkb, Wvb, bq, bk, bv, dtok,
                                                  Qb, Kc, Vtc, 8192, 1024, 1024);
    attn_fwd<<<512, 256, 0, stream>>>(Qb, Kc, Vtc, NbA, Xb);
    gemm_out<<<512, 256, 0, stream>>>(Xb, Wob, bo, out, 8192, 1024, 1024);
}

// Round 23
// 177.431 us; speedup vs baseline: 1.1235x; 1.0073x over previous
//
#include <hip/hip_runtime.h>

typedef unsigned short u16;
typedef unsigned int u32;
typedef __bf16 bf16x8 __attribute__((ext_vector_type(8)));
typedef float f32x4 __attribute__((ext_vector_type(4)));
typedef u16 u16x8 __attribute__((ext_vector_type(8)));
typedef u16 u16x4 __attribute__((ext_vector_type(4)));

typedef __attribute__((address_space(1))) const unsigned char gc_u8;
typedef __attribute__((address_space(3))) unsigned char lds_u8;

__device__ inline void gload16(const void* g, void* l) {
    __builtin_amdgcn_global_load_lds((gc_u8*)g, (lds_u8*)l, 16, 0, 0);
}
__device__ inline u16 f2bf(float f) {
    union { __bf16 h; u16 u; } c; c.h = (__bf16)f; return c.u;
}
__device__ inline float bf2f(u16 u) {
    union { u16 u[2]; float f; } c; c.u[0] = 0; c.u[1] = u; return c.f;
}
__device__ inline void hard_barrier() {
    __builtin_amdgcn_sched_barrier(0);
    __builtin_amdgcn_s_barrier();
    __builtin_amdgcn_sched_barrier(0);
}
#define WAIT_LGKM0() asm volatile("s_waitcnt lgkmcnt(0)" ::: "memory")
#define WAIT_VMCNT(n) asm volatile("s_waitcnt vmcnt(" #n ")" ::: "memory")

// ---------------- merged setup: weight cvt (y<4) + dtok build (y==4, x<4) ----------------
__global__ __launch_bounds__(256) void setup(const float* __restrict__ s0,
                                             const float* __restrict__ s1,
                                             const float* __restrict__ s2,
                                             const float* __restrict__ s3,
                                             u16* __restrict__ d0, u16* __restrict__ d1,
                                             u16* __restrict__ d2, u16* __restrict__ d3,
                                             int n,
                                             const int* __restrict__ mask,
                                             int* __restrict__ dtok,
                                             int* __restrict__ NbA) {
    __shared__ u32 W[64];
    __shared__ u32 Wpre[65];
    const int y = blockIdx.y, t = threadIdx.x;
    if (y < 4) {
        const float* src = (y == 0) ? s0 : (y == 1) ? s1 : (y == 2) ? s2 : s3;
        u16* dst = (y == 0) ? d0 : (y == 1) ? d1 : (y == 2) ? d2 : d3;
        int i = (blockIdx.x * 256 + t) * 4;
        if (i < n) {
            float4 f = *reinterpret_cast<const float4*>(src + i);
            u16x4 u = { f2bf(f.x), f2bf(f.y), f2bf(f.z), f2bf(f.w) };
            *reinterpret_cast<u16x4*>(dst + i) = u;
        }
        return;
    }
    // y == 4: dtok for batch b = blockIdx.x (only x < 4 active)
    const int b = blockIdx.x;
    if (b >= 4) return;
    const int* mrow = mask + b * 2048;
    if (t < 64) {
        u32 wv = 0;
#pragma unroll 8
        for (int j = 0; j < 32; j++) wv |= (mrow[t * 32 + j] ? 1u : 0u) << j;
        W[t] = wv;
    }
    __syncthreads();
    if (t == 0) {
        u32 s = 0;
        for (int i = 0; i < 64; i++) { Wpre[i] = s; s += __popc(W[i]); }
        Wpre[64] = s;
        NbA[b] = (int)s;
    }
    __syncthreads();
    const int Nb = (int)Wpre[64];
    const int pad = (Nb + 127) & ~127;
#pragma unroll
    for (int i = 0; i < 8; i++) {
        const int s = t * 8 + i;
        const u32 word = W[s >> 5];
        const int pre = (int)Wpre[s >> 5] + __popc(word & ((1u << (s & 31)) - 1u));
        int v;
        if ((word >> (s & 31)) & 1u) {
            v = pre;
        } else {
            const int slot = Nb + (s - pre);
            v = (slot < pad) ? -(slot + 2) : -1;
        }
        dtok[b * 2048 + s] = v;
    }
}

// ---------------- merged QKV projection GEMM, f32-A via gload_lds, COMPACTING epilogue ----------------
// R19/R22-exact (measured best).
__global__ __launch_bounds__(256) void gemm_qkv(const float* __restrict__ Aq,
                                                const float* __restrict__ Ak,
                                                const float* __restrict__ Av,
                                                const u16* __restrict__ Bq,
                                                const u16* __restrict__ Bk,
                                                const u16* __restrict__ Bv,
                                                const float* __restrict__ bq,
                                                const float* __restrict__ bk,
                                                const float* __restrict__ bv,
                                                const int* __restrict__ dtok,
                                                u16* __restrict__ Cq,
                                                u16* __restrict__ Ck,
                                                u16* __restrict__ Cvp,
                                                int M, int N, int K) {
    __shared__ __align__(16) float Asf[2][128][32];
    __shared__ __align__(16) u16 Bs[2][128][32];
    const int z = blockIdx.z;
    const float* A = (z == 0) ? Aq : (z == 1) ? Ak : Av;
    const u16* B = (z == 0) ? Bq : (z == 1) ? Bk : Bv;
    const float* bias = (z == 0) ? bq : (z == 1) ? bk : bv;

    const int t = threadIdx.x, lane = t & 63, w = t >> 6;
    const int wr = w >> 1, wc = w & 1;
    const int l15 = lane & 15, l16 = lane >> 4;
    const int nwg = gridDim.x, ntiles = N >> 7;
    const int wg = blockIdx.x, chunk = nwg >> 3;
    const int swz = (wg & 7) * chunk + (wg >> 3);
    const int bm = (swz / ntiles) * 128, bn = (swz % ntiles) * 128;
    const int srow = w * 16 + (lane >> 2);
    const int sgrB = ((lane & 3) ^ ((lane >> 3) & 3)) * 8;
    const int gswB = (l16 ^ ((l15 >> 1) & 3)) * 8;
    const int arsub = lane >> 3;
    const int agr = ((lane & 7) ^ (lane >> 3)) * 4;
    const u16* Bb = B + (size_t)bn * K;

    f32x4 acc[4][4];
#pragma unroll
    for (int i = 0; i < 4; i++)
#pragma unroll
        for (int j = 0; j < 4; j++) acc[i][j] = (f32x4){0.f, 0.f, 0.f, 0.f};

    auto stage = [&](int c, int k0) {
#pragma unroll
        for (int ch = 0; ch < 4; ch++)
            gload16(A + (size_t)(bm + ch * 32 + w * 8 + arsub) * K + k0 + agr,
                    &Asf[c][ch * 32 + w * 8][0]);
        gload16(Bb + (size_t)srow * K + k0 + sgrB,        &Bs[c][w * 16][0]);
        gload16(Bb + (size_t)(64 + srow) * K + k0 + sgrB, &Bs[c][64 + w * 16][0]);
    };

    stage(0, 0);
    __syncthreads();

    const int NS = K >> 5;
    for (int i = 0; i < NS; ++i) {
        const int c = i & 1;
        WAIT_LGKM0();
        hard_barrier();
        if (i + 1 < NS) {
            stage(c ^ 1, (i + 1) * 32);
            WAIT_VMCNT(6);
        } else {
            WAIT_VMCNT(0);
        }
        hard_barrier();

        const int key = l15 & 7;
        bf16x8 afr[4], bfr[4];
#pragma unroll
        for (int mi = 0; mi < 4; mi++) {
            const int rr = wr * 64 + mi * 16 + l15;
            f32x4 lo = *(const f32x4*)&Asf[c][rr][((2 * l16) ^ key) * 4];
            f32x4 hi = *(const f32x4*)&Asf[c][rr][((2 * l16 + 1) ^ key) * 4];
            bf16x8 v;
            v[0] = (__bf16)lo[0]; v[1] = (__bf16)lo[1];
            v[2] = (__bf16)lo[2]; v[3] = (__bf16)lo[3];
            v[4] = (__bf16)hi[0]; v[5] = (__bf16)hi[1];
            v[6] = (__bf16)hi[2]; v[7] = (__bf16)hi[3];
            afr[mi] = v;
        }
#pragma unroll
        for (int ni = 0; ni < 4; ni++)
            bfr[ni] = *(const bf16x8*)&Bs[c][wc * 64 + ni * 16 + l15][gswB];
#pragma unroll
        for (int mi = 0; mi < 4; mi++)
#pragma unroll
            for (int ni = 0; ni < 4; ni++)
                acc[mi][ni] = __builtin_amdgcn_mfma_f32_16x16x32_bf16(
                    afr[mi], bfr[ni], acc[mi][ni], 0, 0, 0);
    }

    int dts[4][4];
    if (z != 0) {
#pragma unroll
        for (int mi = 0; mi < 4; mi++) {
            const int r0 = bm + wr * 64 + mi * 16 + l16 * 4;
#pragma unroll
            for (int r = 0; r < 4; r++) dts[mi][r] = dtok[r0 + r];
        }
    }

#pragma unroll
    for (int ni = 0; ni < 4; ni++) {
        const int col = bn + wc * 64 + ni * 16 + l15;
        const float bv2 = bias[col];
#pragma unroll
        for (int mi = 0; mi < 4; mi++) {
            const int r0 = bm + wr * 64 + mi * 16 + l16 * 4;
            const int bb = r0 >> 11;
            if (z == 0) {
#pragma unroll
                for (int r = 0; r < 4; r++)
                    Cq[(size_t)(r0 + r) * N + col] = f2bf(acc[mi][ni][r] + bv2);
            } else if (z == 1) {
#pragma unroll
                for (int r = 0; r < 4; r++) {
                    const int d = dts[mi][r];
                    if (d >= 0)
                        Ck[((size_t)(bb * 2048 + d)) * 1024 + col] =
                            f2bf(acc[mi][ni][r] + bv2);
                    else if (d != -1)
                        Ck[((size_t)(bb * 2048 + (-d - 2))) * 1024 + col] = 0;
                }
            } else {
                const int hh = col >> 6, dk = col & 63;
                u16* dst = Cvp + (((size_t)(bb * 16 + hh) * 64 + dk) << 11);
#pragma unroll
                for (int r = 0; r < 4; r++) {
                    const int d = dts[mi][r];
                    if (d >= 0) dst[d] = f2bf(acc[mi][ni][r] + bv2);
                    else if (d != -1) dst[-d - 2] = 0;
                }
            }
        }
    }
}

// ---------------- out-projection GEMM (f32 out), swizzled LDS — R19/R22 proven ----------------
__global__ __launch_bounds__(256) void gemm_out(const u16* __restrict__ A,
                                                const u16* __restrict__ B,
                                                const float* __restrict__ bias,
                                                float* __restrict__ Cv,
                                                int M, int N, int K) {
    __shared__ __align__(16) u16 As[2][128][32];
    __shared__ __align__(16) u16 Bs[2][128][32];
    const int t = threadIdx.x, lane = t & 63, w = t >> 6;
    const int wr = w >> 1, wc = w & 1;
    const int l15 = lane & 15, l16 = lane >> 4;
    const int nwg = gridDim.x, ntiles = N >> 7;
    const int wg = blockIdx.x, chunk = nwg >> 3;
    const int swz = (wg & 7) * chunk + (wg >> 3);
    const int bm = (swz / ntiles) * 128, bn = (swz % ntiles) * 128;
    const int srow = w * 16 + (lane >> 2);
    const int sgrB = ((lane & 3) ^ ((lane >> 3) & 3)) * 8;
    const int gswB = (l16 ^ ((l15 >> 1) & 3)) * 8;
    const u16* Ab = A + (size_t)bm * K;
    const u16* Bb = B + (size_t)bn * K;

    f32x4 acc[4][4];
#pragma unroll
    for (int i = 0; i < 4; i++)
#pragma unroll
        for (int j = 0; j < 4; j++) acc[i][j] = (f32x4){0.f, 0.f, 0.f, 0.f};

    auto stage = [&](int c, int k0) {
        gload16(Ab + (size_t)srow * K + k0 + sgrB,        &As[c][w * 16][0]);
        gload16(Ab + (size_t)(64 + srow) * K + k0 + sgrB, &As[c][64 + w * 16][0]);
        gload16(Bb + (size_t)srow * K + k0 + sgrB,        &Bs[c][w * 16][0]);
        gload16(Bb + (size_t)(64 + srow) * K + k0 + sgrB, &Bs[c][64 + w * 16][0]);
    };

    stage(0, 0);
    __syncthreads();

    const int NS = K >> 5;
    for (int i = 0; i < NS; ++i) {
        const int c = i & 1;
        WAIT_LGKM0();
        hard_barrier();
        if (i + 1 < NS) {
            stage(c ^ 1, (i + 1) * 32);
            WAIT_VMCNT(4);
        } else {
            WAIT_VMCNT(0);
        }
        hard_barrier();

        bf16x8 afr[4], bfr[4];
#pragma unroll
        for (int mi = 0; mi < 4; mi++)
            afr[mi] = *(const bf16x8*)&As[c][wr * 64 + mi * 16 + l15][gswB];
#pragma unroll
        for (int ni = 0; ni < 4; ni++)
            bfr[ni] = *(const bf16x8*)&Bs[c][wc * 64 + ni * 16 + l15][gswB];
#pragma unroll
        for (int mi = 0; mi < 4; mi++)
#pragma unroll
            for (int ni = 0; ni < 4; ni++)
                acc[mi][ni] = __builtin_amdgcn_mfma_f32_16x16x32_bf16(
                    afr[mi], bfr[ni], acc[mi][ni], 0, 0, 0);
    }

#pragma unroll
    for (int ni = 0; ni < 4; ni++) {
        const int col = bn + wc * 64 + ni * 16 + l15;
        const float bv = bias[col];
#pragma unroll
        for (int mi = 0; mi < 4; mi++) {
            const int r0 = bm + wr * 64 + mi * 16 + l16 * 4;
#pragma unroll
            for (int r = 0; r < 4; r++)
                Cv[(size_t)(r0 + r) * N + col] = acc[mi][ni][r] + bv;
        }
    }
}

// ---------------- flash attention over COMPACTED keys — R22 + ones-for-full-tiles ----------------
__global__ __launch_bounds__(256, 2) void attn_fwd(const u16* __restrict__ Q,
                                                   const u16* __restrict__ Kg,
                                                   const u16* __restrict__ Vt,
                                                   const int* __restrict__ NbA,
                                                   u16* __restrict__ O) {
    constexpr int S = 2048, D = 1024;
    __shared__ __align__(16) u16 Kl[2][2][2][64][32];
    __shared__ __align__(16) u16 Vl[2][2][2][64][32];
    __shared__ __align__(16) u16 Pl[4][16][68];
    __shared__ __align__(16) u16 Ml[2048];
    const int t = threadIdx.x, lane = t & 63, w = t >> 6;
    const int l15 = lane & 15, l16 = lane >> 4;
    const int wg = blockIdx.x;
    const int swz = (wg & 7) * 64 + (wg >> 3);
    const int q0 = (swz & 7) * 256, hd = (swz >> 3) & 15, b = swz >> 7;
    const int qb = q0 + w * 64;
    const int srow = w * 16 + (lane >> 2);
    const int sgr = ((lane & 3) ^ ((lane >> 3) & 3)) * 8;
    const int gsw8 = (l16 ^ ((l15 >> 1) & 3)) * 8;

    const int Nb = NbA[b];
    const int nt = (Nb + 127) >> 7;

    const u16* Khead = Kg + (size_t)b * S * D;
    const u16* Vthead = Vt + (size_t)(b * 16 + hd) * 64 * 2048;

    auto stage = [&](int c, int kt) {
#pragma unroll
        for (int kg = 0; kg < 2; kg++) {
            const int k0 = kt + kg * 64;
            gload16(Khead + (size_t)(k0 + srow) * D + hd * 64 + sgr,      &Kl[c][kg][0][w * 16][0]);
            gload16(Khead + (size_t)(k0 + srow) * D + hd * 64 + 32 + sgr, &Kl[c][kg][1][w * 16][0]);
            gload16(Vthead + (size_t)srow * 2048 + k0 + sgr,              &Vl[c][kg][0][w * 16][0]);
            gload16(Vthead + (size_t)srow * 2048 + k0 + 32 + sgr,         &Vl[c][kg][1][w * 16][0]);
        }
    };

    stage(0, 0);
    {
        u16x8 mv;
#pragma unroll
        for (int j = 0; j < 8; j++) mv[j] = (t * 8 + j < Nb) ? (u16)0x3F80 : (u16)0;
        *(u16x8*)&Ml[t * 8] = mv;
    }

    constexpr float QSCALE = 0.125f * 1.44269504f;
    bf16x8 aq[4][2];
#pragma unroll
    for (int qt = 0; qt < 4; qt++)
#pragma unroll
        for (int ks = 0; ks < 2; ks++) {
            const size_t qi = ((size_t)b * S + qb + qt * 16 + l15) * D +
                              hd * 64 + ks * 32 + l16 * 8;
            u16x8 raw = *(const u16x8*)&Q[qi];
            bf16x8 qv;
#pragma unroll
            for (int i = 0; i < 8; i++) qv[i] = (__bf16)(bf2f(raw[i]) * QSCALE);
            aq[qt][ks] = qv;
        }

    bf16x8 ones;
#pragma unroll
    for (int i = 0; i < 8; i++) ones[i] = (__bf16)1.0f;

    f32x4 acc[4][4];
    f32x4 accl[4];
#pragma unroll
    for (int qt = 0; qt < 4; qt++) {
        accl[qt] = (f32x4){0.f, 0.f, 0.f, 0.f};
#pragma unroll
        for (int dt = 0; dt < 4; dt++) acc[qt][dt] = (f32x4){0.f, 0.f, 0.f, 0.f};
    }

    __syncthreads();

    for (int tile = 0; tile < nt; ++tile) {
        const int c = tile & 1;
        const int cur = tile * 128;
        const bool lastTile = (tile + 1 >= nt);
        WAIT_LGKM0();
        hard_barrier();
        if (!lastTile) {
            stage(c ^ 1, cur + 128);
            WAIT_VMCNT(8);
        } else {
            WAIT_VMCNT(0);
        }
        hard_barrier();

#pragma unroll
        for (int kg = 0; kg < 2; kg++) {
            bf16x8 kf0[4], kf1[4], vf0[4], vf1[4];
#pragma unroll
            for (int k4 = 0; k4 < 4; k4++) {
                kf0[k4] = *(const bf16x8*)&Kl[c][kg][0][k4 * 16 + l15][gsw8];
                kf1[k4] = *(const bf16x8*)&Kl[c][kg][1][k4 * 16 + l15][gsw8];
            }
#pragma unroll
            for (int dt = 0; dt < 4; dt++) {
                vf0[dt] = *(const bf16x8*)&Vl[c][kg][0][dt * 16 + l15][gsw8];
                vf1[dt] = *(const bf16x8*)&Vl[c][kg][1][dt * 16 + l15][gsw8];
            }
            // lsum fragments: all-1 except (possibly) in the final tile (pad keys).
            bf16x8 mv0, mv1;
            if (lastTile) {
                const int kbase = cur + kg * 64;
                mv0 = *(const bf16x8*)&Ml[kbase + l16 * 8];
                mv1 = *(const bf16x8*)&Ml[kbase + 32 + l16 * 8];
            } else {
                mv0 = ones;
                mv1 = ones;
            }

#pragma unroll
            for (int qt = 0; qt < 4; qt++) {
#pragma unroll
                for (int k4 = 0; k4 < 4; k4++) {
                    f32x4 z = (f32x4){0.f, 0.f, 0.f, 0.f};
                    z = __builtin_amdgcn_mfma_f32_16x16x32_bf16(kf0[k4], aq[qt][0], z, 0, 0, 0);
                    z = __builtin_amdgcn_mfma_f32_16x16x32_bf16(kf1[k4], aq[qt][1], z, 0, 0, 0);
                    u16x4 pk;
#pragma unroll
                    for (int r = 0; r < 4; r++)
                        pk[r] = f2bf(__builtin_amdgcn_exp2f(z[r]));
                    *(u16x4*)&Pl[w][l15][k4 * 16 + l16 * 4] = pk;
                }
                bf16x8 pa0 = *(const bf16x8*)&Pl[w][l15][l16 * 8];
                bf16x8 pa1 = *(const bf16x8*)&Pl[w][l15][32 + l16 * 8];
                accl[qt] = __builtin_amdgcn_mfma_f32_16x16x32_bf16(pa0, mv0, accl[qt], 0, 0, 0);
                accl[qt] = __builtin_amdgcn_mfma_f32_16x16x32_bf16(pa1, mv1, accl[qt], 0, 0, 0);
#pragma unroll
                for (int dt = 0; dt < 4; dt++) {
                    acc[qt][dt] = __builtin_amdgcn_mfma_f32_16x16x32_bf16(
                        pa0, vf0[dt], acc[qt][dt], 0, 0, 0);
                    acc[qt][dt] = __builtin_amdgcn_mfma_f32_16x16x32_bf16(
                        pa1, vf1[dt], acc[qt][dt], 0, 0, 0);
                }
            }
        }
    }

#pragma unroll
    for (int qt = 0; qt < 4; qt++) {
        f32x4 inv;
#pragma unroll
        for (int r = 0; r < 4; r++) inv[r] = 1.f / accl[qt][r];
#pragma unroll
        for (int dt = 0; dt < 4; dt++)
#pragma unroll
            for (int r = 0; r < 4; r++) {
                const int tok = qb + qt * 16 + l16 * 4 + r;
                O[((size_t)b * S + tok) * D + hd * 64 + dt * 16 + l15] =
                    f2bf(acc[qt][dt][r] * inv[r]);
            }
    }
}

extern "C" void kernel_launch(void* const* d_in, const int* in_sizes, int n_in,
                              void* d_out, int out_size, void* d_ws, size_t ws_size,
                              hipStream_t stream) {
    const float* query = (const float*)d_in[0];
    const float* key   = (const float*)d_in[1];
    const float* value = (const float*)d_in[2];
    const int*   mask  = (const int*)d_in[3];
    const float* Wq = (const float*)d_in[4];
    const float* bq = (const float*)d_in[5];
    const float* Wk = (const float*)d_in[6];
    const float* bk = (const float*)d_in[7];
    const float* Wv = (const float*)d_in[8];
    const float* bv = (const float*)d_in[9];
    const float* Wo = (const float*)d_in[10];
    const float* bo = (const float*)d_in[11];
    float* out = (float*)d_out;

    constexpr int S = 2048, D = 1024;
    constexpr size_t MSZ = (size_t)4 * S * D;   // 8388608
    constexpr size_t WSZ = (size_t)D * D;       // 1048576
    const size_t need = 4 * WSZ * 2 + 2 * MSZ * 2 + 8192 * 4 + 64;
    if (ws_size < need) return;

    char* p = (char*)d_ws;
    u16* Wqb = (u16*)p; p += WSZ * 2;
    u16* Wkb = (u16*)p; p += WSZ * 2;
    u16* Wvb = (u16*)p; p += WSZ * 2;
    u16* Wob = (u16*)p; p += WSZ * 2;
    u16* Xb  = (u16*)p; p += MSZ * 2;
    u16* Qb  = (u16*)p; p += MSZ * 2;
    int* dtok = (int*)p; p += 8192 * 4;
    int* NbA = (int*)p; p += 64;
    u16* Kc  = (u16*)d_out;            // compacted K rows (pad rows zeroed in-epilogue)
    u16* Vtc = (u16*)d_out + MSZ;      // compacted V^T (pad slots zeroed in-epilogue)

    setup<<<dim3(WSZ / 1024, 5), 256, 0, stream>>>(Wq, Wk, Wv, Wo,
                                                   Wqb, Wkb, Wvb, Wob, (int)WSZ,
                                                   mask, dtok, NbA);
    gemm_qkv<<<dim3(512, 1, 3), 256, 0, stream>>>(query, key, value,
                                                  Wqb, Wkb, Wvb, bq, bk, bv, dtok,
                                                  Qb, Kc, Vtc, 8192, 1024, 1024);
    attn_fwd<<<512, 256, 0, stream>>>(Qb, Kc, Vtc, NbA, Xb);
    gemm_out<<<512, 256, 0, stream>>>(Xb, Wob, bo, out, 8192, 1024, 1024);
}

// Round 24
// 177.099 us; speedup vs baseline: 1.1256x; 1.0019x over previous
//
#include <hip/hip_runtime.h>

typedef unsigned short u16;
typedef unsigned int u32;
typedef __bf16 bf16x8 __attribute__((ext_vector_type(8)));
typedef float f32x4 __attribute__((ext_vector_type(4)));
typedef u16 u16x8 __attribute__((ext_vector_type(8)));
typedef u16 u16x4 __attribute__((ext_vector_type(4)));

typedef __attribute__((address_space(1))) const unsigned char gc_u8;
typedef __attribute__((address_space(3))) unsigned char lds_u8;

__device__ inline void gload16(const void* g, void* l) {
    __builtin_amdgcn_global_load_lds((gc_u8*)g, (lds_u8*)l, 16, 0, 0);
}
__device__ inline u16 f2bf(float f) {
    union { __bf16 h; u16 u; } c; c.h = (__bf16)f; return c.u;
}
__device__ inline float bf2f(u16 u) {
    union { u16 u[2]; float f; } c; c.u[0] = 0; c.u[1] = u; return c.f;
}
__device__ inline void hard_barrier() {
    __builtin_amdgcn_sched_barrier(0);
    __builtin_amdgcn_s_barrier();
    __builtin_amdgcn_sched_barrier(0);
}
#define WAIT_LGKM0() asm volatile("s_waitcnt lgkmcnt(0)" ::: "memory")
#define WAIT_VMCNT(n) asm volatile("s_waitcnt vmcnt(" #n ")" ::: "memory")

// ---------------- merged setup: weight cvt (y<4) + dtok build (y==4, x<4) ----------------
__global__ __launch_bounds__(256) void setup(const float* __restrict__ s0,
                                             const float* __restrict__ s1,
                                             const float* __restrict__ s2,
                                             const float* __restrict__ s3,
                                             u16* __restrict__ d0, u16* __restrict__ d1,
                                             u16* __restrict__ d2, u16* __restrict__ d3,
                                             int n,
                                             const int* __restrict__ mask,
                                             int* __restrict__ dtok,
                                             int* __restrict__ NbA) {
    __shared__ u32 W[64];
    __shared__ u32 Wpre[65];
    const int y = blockIdx.y, t = threadIdx.x;
    if (y < 4) {
        const float* src = (y == 0) ? s0 : (y == 1) ? s1 : (y == 2) ? s2 : s3;
        u16* dst = (y == 0) ? d0 : (y == 1) ? d1 : (y == 2) ? d2 : d3;
        int i = (blockIdx.x * 256 + t) * 4;
        if (i < n) {
            float4 f = *reinterpret_cast<const float4*>(src + i);
            u16x4 u = { f2bf(f.x), f2bf(f.y), f2bf(f.z), f2bf(f.w) };
            *reinterpret_cast<u16x4*>(dst + i) = u;
        }
        return;
    }
    // y == 4: dtok for batch b = blockIdx.x (only x < 4 active)
    const int b = blockIdx.x;
    if (b >= 4) return;
    const int* mrow = mask + b * 2048;
    if (t < 64) {
        u32 wv = 0;
#pragma unroll 8
        for (int j = 0; j < 32; j++) wv |= (mrow[t * 32 + j] ? 1u : 0u) << j;
        W[t] = wv;
    }
    __syncthreads();
    if (t == 0) {
        u32 s = 0;
        for (int i = 0; i < 64; i++) { Wpre[i] = s; s += __popc(W[i]); }
        Wpre[64] = s;
        NbA[b] = (int)s;
    }
    __syncthreads();
    const int Nb = (int)Wpre[64];
    const int pad = (Nb + 127) & ~127;
#pragma unroll
    for (int i = 0; i < 8; i++) {
        const int s = t * 8 + i;
        const u32 word = W[s >> 5];
        const int pre = (int)Wpre[s >> 5] + __popc(word & ((1u << (s & 31)) - 1u));
        int v;
        if ((word >> (s & 31)) & 1u) {
            v = pre;
        } else {
            const int slot = Nb + (s - pre);
            v = (slot < pad) ? -(slot + 2) : -1;
        }
        dtok[b * 2048 + s] = v;
    }
}

// ---------------- merged QKV projection GEMM, f32-A via gload_lds, COMPACTING epilogue ----------------
__global__ __launch_bounds__(256) void gemm_qkv(const float* __restrict__ Aq,
                                                const float* __restrict__ Ak,
                                                const float* __restrict__ Av,
                                                const u16* __restrict__ Bq,
                                                const u16* __restrict__ Bk,
                                                const u16* __restrict__ Bv,
                                                const float* __restrict__ bq,
                                                const float* __restrict__ bk,
                                                const float* __restrict__ bv,
                                                const int* __restrict__ dtok,
                                                u16* __restrict__ Cq,
                                                u16* __restrict__ Ck,
                                                u16* __restrict__ Cvp,
                                                int M, int N, int K) {
    __shared__ __align__(16) float Asf[2][128][32];
    __shared__ __align__(16) u16 Bs[2][128][32];
    const int z = blockIdx.z;
    const float* A = (z == 0) ? Aq : (z == 1) ? Ak : Av;
    const u16* B = (z == 0) ? Bq : (z == 1) ? Bk : Bv;
    const float* bias = (z == 0) ? bq : (z == 1) ? bk : bv;

    const int t = threadIdx.x, lane = t & 63, w = t >> 6;
    const int wr = w >> 1, wc = w & 1;
    const int l15 = lane & 15, l16 = lane >> 4;
    const int nwg = gridDim.x, ntiles = N >> 7;
    const int wg = blockIdx.x, chunk = nwg >> 3;
    const int swz = (wg & 7) * chunk + (wg >> 3);
    const int bm = (swz / ntiles) * 128, bn = (swz % ntiles) * 128;
    const int srow = w * 16 + (lane >> 2);
    const int sgrB = ((lane & 3) ^ ((lane >> 3) & 3)) * 8;
    const int gswB = (l16 ^ ((l15 >> 1) & 3)) * 8;
    const int arsub = lane >> 3;
    const int agr = ((lane & 7) ^ (lane >> 3)) * 4;
    const u16* Bb = B + (size_t)bn * K;

    f32x4 acc[4][4];
#pragma unroll
    for (int i = 0; i < 4; i++)
#pragma unroll
        for (int j = 0; j < 4; j++) acc[i][j] = (f32x4){0.f, 0.f, 0.f, 0.f};

    auto stage = [&](int c, int k0) {
#pragma unroll
        for (int ch = 0; ch < 4; ch++)
            gload16(A + (size_t)(bm + ch * 32 + w * 8 + arsub) * K + k0 + agr,
                    &Asf[c][ch * 32 + w * 8][0]);
        gload16(Bb + (size_t)srow * K + k0 + sgrB,        &Bs[c][w * 16][0]);
        gload16(Bb + (size_t)(64 + srow) * K + k0 + sgrB, &Bs[c][64 + w * 16][0]);
    };

    stage(0, 0);
    __syncthreads();

    const int NS = K >> 5;
    for (int i = 0; i < NS; ++i) {
        const int c = i & 1;
        WAIT_LGKM0();
        hard_barrier();
        if (i + 1 < NS) {
            stage(c ^ 1, (i + 1) * 32);
            WAIT_VMCNT(6);
        } else {
            WAIT_VMCNT(0);
        }
        hard_barrier();

        const int key = l15 & 7;
        bf16x8 afr[4], bfr[4];
#pragma unroll
        for (int mi = 0; mi < 4; mi++) {
            const int rr = wr * 64 + mi * 16 + l15;
            f32x4 lo = *(const f32x4*)&Asf[c][rr][((2 * l16) ^ key) * 4];
            f32x4 hi = *(const f32x4*)&Asf[c][rr][((2 * l16 + 1) ^ key) * 4];
            bf16x8 v;
            v[0] = (__bf16)lo[0]; v[1] = (__bf16)lo[1];
            v[2] = (__bf16)lo[2]; v[3] = (__bf16)lo[3];
            v[4] = (__bf16)hi[0]; v[5] = (__bf16)hi[1];
            v[6] = (__bf16)hi[2]; v[7] = (__bf16)hi[3];
            afr[mi] = v;
        }
#pragma unroll
        for (int ni = 0; ni < 4; ni++)
            bfr[ni] = *(const bf16x8*)&Bs[c][wc * 64 + ni * 16 + l15][gswB];
#pragma unroll
        for (int mi = 0; mi < 4; mi++)
#pragma unroll
            for (int ni = 0; ni < 4; ni++)
                acc[mi][ni] = __builtin_amdgcn_mfma_f32_16x16x32_bf16(
                    afr[mi], bfr[ni], acc[mi][ni], 0, 0, 0);
    }

    int dts[4][4];
    if (z != 0) {
#pragma unroll
        for (int mi = 0; mi < 4; mi++) {
            const int r0 = bm + wr * 64 + mi * 16 + l16 * 4;
#pragma unroll
            for (int r = 0; r < 4; r++) dts[mi][r] = dtok[r0 + r];
        }
    }

#pragma unroll
    for (int ni = 0; ni < 4; ni++) {
        const int col = bn + wc * 64 + ni * 16 + l15;
        const float bv2 = bias[col];
#pragma unroll
        for (int mi = 0; mi < 4; mi++) {
            const int r0 = bm + wr * 64 + mi * 16 + l16 * 4;
            const int bb = r0 >> 11;
            if (z == 0) {
#pragma unroll
                for (int r = 0; r < 4; r++)
                    Cq[(size_t)(r0 + r) * N + col] = f2bf(acc[mi][ni][r] + bv2);
            } else if (z == 1) {
#pragma unroll
                for (int r = 0; r < 4; r++) {
                    const int d = dts[mi][r];
                    if (d >= 0)
                        Ck[((size_t)(bb * 2048 + d)) * 1024 + col] =
                            f2bf(acc[mi][ni][r] + bv2);
                    else if (d != -1)
                        Ck[((size_t)(bb * 2048 + (-d - 2))) * 1024 + col] = 0;
                }
            } else {
                const int hh = col >> 6, dk = col & 63;
                u16* dst = Cvp + (((size_t)(bb * 16 + hh) * 64 + dk) << 11);
#pragma unroll
                for (int r = 0; r < 4; r++) {
                    const int d = dts[mi][r];
                    if (d >= 0) dst[d] = f2bf(acc[mi][ni][r] + bv2);
                    else if (d != -1) dst[-d - 2] = 0;
                }
            }
        }
    }
}

// ---------------- out-projection GEMM (f32 out), swizzled LDS ----------------
__global__ __launch_bounds__(256) void gemm_out(const u16* __restrict__ A,
                                                const u16* __restrict__ B,
                                                const float* __restrict__ bias,
                                                float* __restrict__ Cv,
                                                int M, int N, int K) {
    __shared__ __align__(16) u16 As[2][128][32];
    __shared__ __align__(16) u16 Bs[2][128][32];
    const int t = threadIdx.x, lane = t & 63, w = t >> 6;
    const int wr = w >> 1, wc = w & 1;
    const int l15 = lane & 15, l16 = lane >> 4;
    const int nwg = gridDim.x, ntiles = N >> 7;
    const int wg = blockIdx.x, chunk = nwg >> 3;
    const int swz = (wg & 7) * chunk + (wg >> 3);
    const int bm = (swz / ntiles) * 128, bn = (swz % ntiles) * 128;
    const int srow = w * 16 + (lane >> 2);
    const int sgrB = ((lane & 3) ^ ((lane >> 3) & 3)) * 8;
    const int gswB = (l16 ^ ((l15 >> 1) & 3)) * 8;
    const u16* Ab = A + (size_t)bm * K;
    const u16* Bb = B + (size_t)bn * K;

    f32x4 acc[4][4];
#pragma unroll
    for (int i = 0; i < 4; i++)
#pragma unroll
        for (int j = 0; j < 4; j++) acc[i][j] = (f32x4){0.f, 0.f, 0.f, 0.f};

    auto stage = [&](int c, int k0) {
        gload16(Ab + (size_t)srow * K + k0 + sgrB,        &As[c][w * 16][0]);
        gload16(Ab + (size_t)(64 + srow) * K + k0 + sgrB, &As[c][64 + w * 16][0]);
        gload16(Bb + (size_t)srow * K + k0 + sgrB,        &Bs[c][w * 16][0]);
        gload16(Bb + (size_t)(64 + srow) * K + k0 + sgrB, &Bs[c][64 + w * 16][0]);
    };

    stage(0, 0);
    __syncthreads();

    const int NS = K >> 5;
    for (int i = 0; i < NS; ++i) {
        const int c = i & 1;
        WAIT_LGKM0();
        hard_barrier();
        if (i + 1 < NS) {
            stage(c ^ 1, (i + 1) * 32);
            WAIT_VMCNT(4);
        } else {
            WAIT_VMCNT(0);
        }
        hard_barrier();

        bf16x8 afr[4], bfr[4];
#pragma unroll
        for (int mi = 0; mi < 4; mi++)
            afr[mi] = *(const bf16x8*)&As[c][wr * 64 + mi * 16 + l15][gswB];
#pragma unroll
        for (int ni = 0; ni < 4; ni++)
            bfr[ni] = *(const bf16x8*)&Bs[c][wc * 64 + ni * 16 + l15][gswB];
#pragma unroll
        for (int mi = 0; mi < 4; mi++)
#pragma unroll
            for (int ni = 0; ni < 4; ni++)
                acc[mi][ni] = __builtin_amdgcn_mfma_f32_16x16x32_bf16(
                    afr[mi], bfr[ni], acc[mi][ni], 0, 0, 0);
    }

#pragma unroll
    for (int ni = 0; ni < 4; ni++) {
        const int col = bn + wc * 64 + ni * 16 + l15;
        const float bv = bias[col];
#pragma unroll
        for (int mi = 0; mi < 4; mi++) {
            const int r0 = bm + wr * 64 + mi * 16 + l16 * 4;
#pragma unroll
            for (int r = 0; r < 4; r++)
                Cv[(size_t)(r0 + r) * N + col] = acc[mi][ni][r] + bv;
        }
    }
}

// ---------------- flash attention over COMPACTED keys ----------------
__global__ __launch_bounds__(256, 2) void attn_fwd(const u16* __restrict__ Q,
                                                   const u16* __restrict__ Kg,
                                                   const u16* __restrict__ Vt,
                                                   const int* __restrict__ NbA,
                                                   u16* __restrict__ O) {
    constexpr int S = 2048, D = 1024;
    __shared__ __align__(16) u16 Kl[2][2][2][64][32];
    __shared__ __align__(16) u16 Vl[2][2][2][64][32];
    __shared__ __align__(16) u16 Pl[4][16][68];
    __shared__ __align__(16) u16 Ml[2048];
    const int t = threadIdx.x, lane = t & 63, w = t >> 6;
    const int l15 = lane & 15, l16 = lane >> 4;
    const int wg = blockIdx.x;
    const int swz = (wg & 7) * 64 + (wg >> 3);
    const int q0 = (swz & 7) * 256, hd = (swz >> 3) & 15, b = swz >> 7;
    const int qb = q0 + w * 64;
    const int srow = w * 16 + (lane >> 2);
    const int sgr = ((lane & 3) ^ ((lane >> 3) & 3)) * 8;
    const int gsw8 = (l16 ^ ((l15 >> 1) & 3)) * 8;

    const int Nb = NbA[b];
    const int nt = (Nb + 127) >> 7;

    const u16* Khead = Kg + (size_t)b * S * D;
    const u16* Vthead = Vt + (size_t)(b * 16 + hd) * 64 * 2048;

    auto stage = [&](int c, int kt) {
#pragma unroll
        for (int kg = 0; kg < 2; kg++) {
            const int k0 = kt + kg * 64;
            gload16(Khead + (size_t)(k0 + srow) * D + hd * 64 + sgr,      &Kl[c][kg][0][w * 16][0]);
            gload16(Khead + (size_t)(k0 + srow) * D + hd * 64 + 32 + sgr, &Kl[c][kg][1][w * 16][0]);
            gload16(Vthead + (size_t)srow * 2048 + k0 + sgr,              &Vl[c][kg][0][w * 16][0]);
            gload16(Vthead + (size_t)srow * 2048 + k0 + 32 + sgr,         &Vl[c][kg][1][w * 16][0]);
        }
    };

    stage(0, 0);
    {
        u16x8 mv;
#pragma unroll
        for (int j = 0; j < 8; j++) mv[j] = (t * 8 + j < Nb) ? (u16)0x3F80 : (u16)0;
        *(u16x8*)&Ml[t * 8] = mv;
    }

    constexpr float QSCALE = 0.125f * 1.44269504f;
    bf16x8 aq[4][2];
#pragma unroll
    for (int qt = 0; qt < 4; qt++)
#pragma unroll
        for (int ks = 0; ks < 2; ks++) {
            const size_t qi = ((size_t)b * S + qb + qt * 16 + l15) * D +
                              hd * 64 + ks * 32 + l16 * 8;
            u16x8 raw = *(const u16x8*)&Q[qi];
            bf16x8 qv;
#pragma unroll
            for (int i = 0; i < 8; i++) qv[i] = (__bf16)(bf2f(raw[i]) * QSCALE);
            aq[qt][ks] = qv;
        }

    bf16x8 ones;
#pragma unroll
    for (int i = 0; i < 8; i++) ones[i] = (__bf16)1.0f;

    f32x4 acc[4][4];
    f32x4 accl[4];
#pragma unroll
    for (int qt = 0; qt < 4; qt++) {
        accl[qt] = (f32x4){0.f, 0.f, 0.f, 0.f};
#pragma unroll
        for (int dt = 0; dt < 4; dt++) acc[qt][dt] = (f32x4){0.f, 0.f, 0.f, 0.f};
    }

    __syncthreads();

    for (int tile = 0; tile < nt; ++tile) {
        const int c = tile & 1;
        const int cur = tile * 128;
        const bool lastTile = (tile + 1 >= nt);
        WAIT_LGKM0();
        hard_barrier();
        if (!lastTile) {
            stage(c ^ 1, cur + 128);
            WAIT_VMCNT(8);
        } else {
            WAIT_VMCNT(0);
        }
        hard_barrier();

#pragma unroll
        for (int kg = 0; kg < 2; kg++) {
            bf16x8 kf0[4], kf1[4], vf0[4], vf1[4];
#pragma unroll
            for (int k4 = 0; k4 < 4; k4++) {
                kf0[k4] = *(const bf16x8*)&Kl[c][kg][0][k4 * 16 + l15][gsw8];
                kf1[k4] = *(const bf16x8*)&Kl[c][kg][1][k4 * 16 + l15][gsw8];
            }
#pragma unroll
            for (int dt = 0; dt < 4; dt++) {
                vf0[dt] = *(const bf16x8*)&Vl[c][kg][0][dt * 16 + l15][gsw8];
                vf1[dt] = *(const bf16x8*)&Vl[c][kg][1][dt * 16 + l15][gsw8];
            }
            bf16x8 mv0, mv1;
            if (lastTile) {
                const int kbase = cur + kg * 64;
                mv0 = *(const bf16x8*)&Ml[kbase + l16 * 8];
                mv1 = *(const bf16x8*)&Ml[kbase + 32 + l16 * 8];
            } else {
                mv0 = ones;
                mv1 = ones;
            }

#pragma unroll
            for (int qt = 0; qt < 4; qt++) {
#pragma unroll
                for (int k4 = 0; k4 < 4; k4++) {
                    f32x4 z = (f32x4){0.f, 0.f, 0.f, 0.f};
                    z = __builtin_amdgcn_mfma_f32_16x16x32_bf16(kf0[k4], aq[qt][0], z, 0, 0, 0);
                    z = __builtin_amdgcn_mfma_f32_16x16x32_bf16(kf1[k4], aq[qt][1], z, 0, 0, 0);
                    u16x4 pk;
#pragma unroll
                    for (int r = 0; r < 4; r++)
                        pk[r] = f2bf(__builtin_amdgcn_exp2f(z[r]));
                    *(u16x4*)&Pl[w][l15][k4 * 16 + l16 * 4] = pk;
                }
                bf16x8 pa0 = *(const bf16x8*)&Pl[w][l15][l16 * 8];
                bf16x8 pa1 = *(const bf16x8*)&Pl[w][l15][32 + l16 * 8];
                accl[qt] = __builtin_amdgcn_mfma_f32_16x16x32_bf16(pa0, mv0, accl[qt], 0, 0, 0);
                accl[qt] = __builtin_amdgcn_mfma_f32_16x16x32_bf16(pa1, mv1, accl[qt], 0, 0, 0);
#pragma unroll
                for (int dt = 0; dt < 4; dt++) {
                    acc[qt][dt] = __builtin_amdgcn_mfma_f32_16x16x32_bf16(
                        pa0, vf0[dt], acc[qt][dt], 0, 0, 0);
                    acc[qt][dt] = __builtin_amdgcn_mfma_f32_16x16x32_bf16(
                        pa1, vf1[dt], acc[qt][dt], 0, 0, 0);
                }
            }
        }
    }

#pragma unroll
    for (int qt = 0; qt < 4; qt++) {
        f32x4 inv;
#pragma unroll
        for (int r = 0; r < 4; r++) inv[r] = 1.f / accl[qt][r];
#pragma unroll
        for (int dt = 0; dt < 4; dt++)
#pragma unroll
            for (int r = 0; r < 4; r++) {
                const int tok = qb + qt * 16 + l16 * 4 + r;
                O[((size_t)b * S + tok) * D + hd * 64 + dt * 16 + l15] =
                    f2bf(acc[qt][dt][r] * inv[r]);
            }
    }
}

extern "C" void kernel_launch(void* const* d_in, const int* in_sizes, int n_in,
                              void* d_out, int out_size, void* d_ws, size_t ws_size,
                              hipStream_t stream) {
    const float* query = (const float*)d_in[0];
    const float* key   = (const float*)d_in[1];
    const float* value = (const float*)d_in[2];
    const int*   mask  = (const int*)d_in[3];
    const float* Wq = (const float*)d_in[4];
    const float* bq = (const float*)d_in[5];
    const float* Wk = (const float*)d_in[6];
    const float* bk = (const float*)d_in[7];
    const float* Wv = (const float*)d_in[8];
    const float* bv = (const float*)d_in[9];
    const float* Wo = (const float*)d_in[10];
    const float* bo = (const float*)d_in[11];
    float* out = (float*)d_out;

    constexpr int S = 2048, D = 1024;
    constexpr size_t MSZ = (size_t)4 * S * D;   // 8388608
    constexpr size_t WSZ = (size_t)D * D;       // 1048576
    const size_t need = 4 * WSZ * 2 + 2 * MSZ * 2 + 8192 * 4 + 64;
    if (ws_size < need) return;

    char* p = (char*)d_ws;
    u16* Wqb = (u16*)p; p += WSZ * 2;
    u16* Wkb = (u16*)p; p += WSZ * 2;
    u16* Wvb = (u16*)p; p += WSZ * 2;
    u16* Wob = (u16*)p; p += WSZ * 2;
    u16* Xb  = (u16*)p; p += MSZ * 2;
    u16* Qb  = (u16*)p; p += MSZ * 2;
    int* dtok = (int*)p; p += 8192 * 4;
    int* NbA = (int*)p; p += 64;
    u16* Kc  = (u16*)d_out;            // compacted K rows (pad rows zeroed in-epilogue)
    u16* Vtc = (u16*)d_out + MSZ;      // compacted V^T (pad slots zeroed in-epilogue)

    setup<<<dim3(WSZ / 1024, 5), 256, 0, stream>>>(Wq, Wk, Wv, Wo,
                                                   Wqb, Wkb, Wvb, Wob, (int)WSZ,
                                                   mask, dtok, NbA);
    gemm_qkv<<<dim3(512, 1, 3), 256, 0, stream>>>(query, key, value,
                                                  Wqb, Wkb, Wvb, bq, bk, bv, dtok,
                                                  Qb, Kc, Vtc, 8192, 1024, 1024);
    attn_fwd<<<512, 256, 0, stream>>>(Qb, Kc, Vtc, NbA, Xb);
    gemm_out<<<512, 256, 0, stream>>>(Xb, Wob, bo, out, 8192, 1024, 1024);
}